// Round 9
// baseline (136.617 us; speedup 1.0000x reference)
//
#include <hip/hip_runtime.h>
#include <math.h>

// PRNN J2 plane-strain elastoplasticity scan.
// B=16384, T=128, F=3, MATPTS=16 (P=262144), O=3.
// R9: back to the SCALAR 1-point/thread layout (262144 threads = 4 waves/SIMD,
// the measured-85%-busy regime of R3) with every slot reduction learned since:
// folded radial-return algebra, float4 register prefetch of x, 4-step unroll,
// and a pipelined (one block deferred) 16-lane DPP reduction built from
// schedulable __builtin_amdgcn_update_dpp adds.

#define BLOCK 256
#define BPB 16              // batch elements per block (16 lanes each)
#define TSTEPS 128
#define ROWF (TSTEPS * 3)   // 384 floats per batch row
#define ROWP 388            // padded stride: 16B-aligned

// one fuse-able DPP add stage: v += dpp_mov(v, ctrl), 0-fill.
#define DPP_ADDST(v, ctrl)                                                   \
    v += __int_as_float(__builtin_amdgcn_update_dpp(                         \
        0, __float_as_int(v), (ctrl), 0xf, 0xf, true))

// 16-lane butterfly sum: quad_perm [1,0,3,2] (0xB1), quad_perm [2,3,0,1]
// (0x4E), row_half_mirror (0x141), row_mirror (0x140).
// All 16 lanes of the group end with the group sum.
#define RED16(v)                                                             \
    do { DPP_ADDST(v, 0xB1); DPP_ADDST(v, 0x4E);                             \
         DPP_ADDST(v, 0x141); DPP_ADDST(v, 0x140); } while (0)

__global__ __launch_bounds__(BLOCK, 4)
void prnn_j2_kernel(const float* __restrict__ x,
                    const float* __restrict__ W1,
                    const float* __restrict__ W2,
                    float* __restrict__ out)
{
    constexpr float MU    = (float)(3130.0 / (2.0 * (1.0 + 0.37)));
    constexpr float LAM   = (float)(3130.0 * 0.37 / ((1.0 + 0.37) * (1.0 - 2.0 * 0.37)));
    constexpr float SIG_Y = 64.8f;
    constexpr float H_ISO = 300.0f;
    const float TWO_MU  = 2.0f * MU;
    const float INV_DEN = 1.0f / (3.0f * MU + H_ISO);
    const float K3P     = (3.0f * MU) * INV_DEN;   // k = K3P * f * rq
    const float HP      = H_ISO * INV_DEN;         // yld += HP * f
    const float KBULK   = LAM + TWO_MU * (1.0f / 3.0f);
    const float C_Q2    = 6.0f * MU * MU;

    // +12 floats: harmless one-block-over prefetch on the last iteration
    __shared__ float xs[BPB * ROWP + 12];

    const int tid = threadIdx.x;
    const int g   = tid >> 4;       // local batch 0..15
    const int m   = tid & 15;       // material point 0..15 == lane in group
    const int blockBase = blockIdx.x * (BPB * ROWF);

    // ---- stage x into LDS (coalesced float4 global reads) ----
    {
        const float4* xg = (const float4*)(x + blockBase);
        for (int i4 = tid; i4 < BPB * ROWF / 4; i4 += BLOCK) {
            int b  = i4 / (ROWF / 4);
            int r4 = i4 - b * (ROWF / 4);
            ((float4*)(xs + b * ROWP))[r4] = xg[i4];
        }
    }

    // ---- per-thread scalar weights for point m ----
    float w1[3][3], w2s[3][3];
    #pragma unroll
    for (int c = 0; c < 3; ++c)
        #pragma unroll
        for (int f = 0; f < 3; ++f)
            w1[c][f] = W1[(3 * m + c) * 3 + f];
    #pragma unroll
    for (int o = 0; o < 3; ++o)
        #pragma unroll
        for (int c = 0; c < 3; ++c) {
            float w = W2[o * 48 + 3 * m + c];
            w2s[o][c] = fmaxf(w, 0.0f) + log1pf(expf(-fabsf(w)));  // stable softplus
        }

    __syncthreads();

    float p0 = 0.f, p1 = 0.f, p2 = 0.f, p3 = 0.f;
    float yld = SIG_Y;
    float* xrow = &xs[g * ROWP];
    const float4* xv = (const float4*)xrow;   // g*1552 B, 16B aligned
    const bool wact = (m < 3);

#define J2_PHYS(x0_, x1_, x2_, o0_, o1_, o2_)                                \
  {                                                                          \
    const float x0 = (x0_), x1 = (x1_), x2 = (x2_);                          \
    const float e0 = w1[0][0]*x0 + w1[0][1]*x1 + w1[0][2]*x2;                \
    const float e1 = w1[1][0]*x0 + w1[1][1]*x1 + w1[1][2]*x2;                \
    const float e2 = w1[2][0]*x0 + w1[2][1]*x1 + w1[2][2]*x2;                \
    const float ee_xx = e0 - p0;                                             \
    const float ee_yy = e1 - p1;                                             \
    const float ee_xy = fmaf(0.5f, e2, -p3);                                 \
    const float tr = (ee_xx + ee_yy) - p2;                                   \
    const float c3 = tr * (1.0f / 3.0f);                                     \
    const float exd = ee_xx - c3;                                            \
    const float eyd = ee_yy - c3;                                            \
    const float ezd = -p2 - c3;                                              \
    float u = exd * exd;                                                     \
    u = fmaf(eyd, eyd, u);                                                   \
    u = fmaf(ezd, ezd, u);                                                   \
    u = fmaf(ee_xy * ee_xy, 2.0f, u);                                        \
    const float q2 = fmaxf(C_Q2 * u, 1e-24f);                                \
    const float rq = __builtin_amdgcn_rsqf(q2);                              \
    const float q  = q2 * rq;                                                \
    const float f  = fmaxf(q - yld, 0.0f);                                   \
    yld = fmaf(HP, f, yld);                                                  \
    const float k   = (K3P * f) * rq;                                        \
    const float omk = 1.0f - k;                                              \
    const float pm  = KBULK * tr;                                            \
    const float s0 = fmaf(TWO_MU * exd, omk, pm);                            \
    const float s1 = fmaf(TWO_MU * eyd, omk, pm);                            \
    const float s2 = (TWO_MU * ee_xy) * omk;                                 \
    p0 = fmaf(k, exd, p0);                                                   \
    p1 = fmaf(k, eyd, p1);                                                   \
    p2 = fmaf(k, ezd, p2);                                                   \
    p3 = fmaf(k, ee_xy, p3);                                                 \
    o0_ = w2s[0][0]*s0 + w2s[0][1]*s1 + w2s[0][2]*s2;                        \
    o1_ = w2s[1][0]*s0 + w2s[1][1]*s1 + w2s[1][2]*s2;                        \
    o2_ = w2s[2][0]*s0 + w2s[2][1]*s1 + w2s[2][2]*s2;                        \
  }

// physics for a 4-step block held in A0..A2, outputs into 12 scalars
#define PHYS_BLOCK(r)                                                        \
    J2_PHYS(A0.x, A0.y, A0.z, r[0],  r[1],  r[2]);                           \
    J2_PHYS(A0.w, A1.x, A1.y, r[3],  r[4],  r[5]);                           \
    J2_PHYS(A1.z, A1.w, A2.x, r[6],  r[7],  r[8]);                           \
    J2_PHYS(A2.y, A2.z, A2.w, r[9],  r[10], r[11])

// reduce 12 partials (schedulable DPP) and write block 'bi''s outputs;
// lanes 0..2 write component m for each of the 4 steps
#define RED_WRITE(r, bi)                                                     \
  {                                                                          \
    _Pragma("unroll")                                                        \
    for (int i = 0; i < 12; ++i) { RED16(r[i]); }                            \
    if (wact) {                                                              \
        float* wp = xrow + 12 * (bi) + m;                                    \
        wp[0] = (m == 0) ? r[0] : ((m == 1) ? r[1]  : r[2]);                 \
        wp[3] = (m == 0) ? r[3] : ((m == 1) ? r[4]  : r[5]);                 \
        wp[6] = (m == 0) ? r[6] : ((m == 1) ? r[7]  : r[8]);                 \
        wp[9] = (m == 0) ? r[9] : ((m == 1) ? r[10] : r[11]);                \
    }                                                                        \
  }

    float4 A0 = xv[0], A1 = xv[1], A2 = xv[2];
    float rprev[12];

    // prologue: physics for block 0, reduction deferred
    {
        float4 An0 = xv[3], An1 = xv[4], An2 = xv[5];
        PHYS_BLOCK(rprev);
        A0 = An0; A1 = An1; A2 = An2;
    }

    for (int tb = 1; tb < TSTEPS / 4; ++tb) {
        // prefetch block tb+1 (last iter over-reads into pad)
        float4 An0 = xv[3 * tb + 3];
        float4 An1 = xv[3 * tb + 4];
        float4 An2 = xv[3 * tb + 5];

        float rcur[12];
        PHYS_BLOCK(rcur);          // block tb physics (independent of rprev)
        RED_WRITE(rprev, tb - 1);  // block tb-1 reduction — overlaps physics

        #pragma unroll
        for (int i = 0; i < 12; ++i) rprev[i] = rcur[i];
        A0 = An0; A1 = An1; A2 = An2;
    }

    // epilogue: reduce+write the final block
    RED_WRITE(rprev, TSTEPS / 4 - 1);

#undef PHYS_BLOCK
#undef RED_WRITE
#undef J2_PHYS

    __syncthreads();

    // ---- coalesced float4 flush LDS -> out ----
    {
        float4* og = (float4*)(out + blockBase);
        for (int i4 = tid; i4 < BPB * ROWF / 4; i4 += BLOCK) {
            int b  = i4 / (ROWF / 4);
            int r4 = i4 - b * (ROWF / 4);
            og[i4] = ((const float4*)(xs + b * ROWP))[r4];
        }
    }
}

extern "C" void kernel_launch(void* const* d_in, const int* in_sizes, int n_in,
                              void* d_out, int out_size, void* d_ws, size_t ws_size,
                              hipStream_t stream) {
    const float* x  = (const float*)d_in[0];
    const float* W1 = (const float*)d_in[1];
    const float* W2 = (const float*)d_in[2];
    float* out = (float*)d_out;

    const int B = 16384;
    dim3 grid(B / BPB);   // 1024 blocks
    dim3 block(BLOCK);
    prnn_j2_kernel<<<grid, block, 0, stream>>>(x, W1, W2, out);
}

// Round 10
// 116.748 us; speedup vs baseline: 1.1702x; 1.1702x over previous
//
#include <hip/hip_runtime.h>
#include <math.h>

// PRNN J2 plane-strain elastoplasticity scan.
// B=16384, T=128, F=3, MATPTS=16 (P=262144), O=3.
// R10: packed R7 layout (2 points/thread, 8 lanes/batch, 32 batches/block,
// 2 waves/SIMD) with:
//  * out(t) = M @ x(t) - 2MU * Z(t) reformulation (C p = 2MU p for trace-free
//    p): stress assembly eliminated; Z = sum_p w2s . p_new accumulates with
//    products shared with the p-update; M is a constant 3x3 reduced at init.
//  * scaled yield state Y = yld/(MU*sqrt(6)) working directly on u.
//  * NO LDS: broadcast global_load_dwordx4 of each group's x row (distance-1
//    prefetch), direct predicated global stores by lanes 0..2.

#define BLOCK 256
#define BPB 32              // batch elements per block (8 lanes each)
#define TSTEPS 128
#define ROWF (TSTEPS * 3)   // 384 floats per batch row

typedef float v2 __attribute__((ext_vector_type(2)));

static __device__ __forceinline__ v2 vfma(v2 a, v2 b, v2 c) {
    return __builtin_elementwise_fma(a, b, c);
}
static __device__ __forceinline__ v2 vmax(v2 a, v2 b) {
    return __builtin_elementwise_max(a, b);
}

// schedulable fused-able DPP add stage: v += dpp_mov(v, ctrl), 0-fill
#define DPP_ADDST(v, ctrl)                                                   \
    v += __int_as_float(__builtin_amdgcn_update_dpp(                         \
        0, __float_as_int(v), (ctrl), 0xf, 0xf, true))
// 8-lane butterfly: quad_perm xor1 (0xB1), xor2 (0x4E), row_half_mirror (0x141)
#define RED8(v)                                                              \
    do { DPP_ADDST(v, 0xB1); DPP_ADDST(v, 0x4E); DPP_ADDST(v, 0x141); } while (0)

// batched asm butterfly for the 12 in-loop partials (R7's best-measured form)
#define DPP_ST(r, ctrl) "v_add_f32_dpp %" #r ", %" #r ", %" #r " " ctrl \
                        " row_mask:0xf bank_mask:0xf\n\t"
#define DPP_STAGE(ctrl) \
    DPP_ST(0, ctrl) DPP_ST(1, ctrl) DPP_ST(2, ctrl)  DPP_ST(3, ctrl) \
    DPP_ST(4, ctrl) DPP_ST(5, ctrl) DPP_ST(6, ctrl)  DPP_ST(7, ctrl) \
    DPP_ST(8, ctrl) DPP_ST(9, ctrl) DPP_ST(10, ctrl) DPP_ST(11, ctrl)
#define DPP_BFLY12(a0,a1,a2,a3,a4,a5,a6,a7,a8,a9,a10,a11)                    \
  asm volatile(                                                              \
    "s_nop 1\n\t"                                                            \
    DPP_STAGE("quad_perm:[1,0,3,2]")                                         \
    DPP_STAGE("quad_perm:[2,3,0,1]")                                         \
    DPP_STAGE("row_half_mirror")                                             \
    : "+v"(a0), "+v"(a1), "+v"(a2), "+v"(a3), "+v"(a4), "+v"(a5),            \
      "+v"(a6), "+v"(a7), "+v"(a8), "+v"(a9), "+v"(a10), "+v"(a11))

__global__ __launch_bounds__(BLOCK, 2)
void prnn_j2_kernel(const float* __restrict__ x,
                    const float* __restrict__ W1,
                    const float* __restrict__ W2,
                    float* __restrict__ out)
{
    constexpr float MU    = (float)(3130.0 / (2.0 * (1.0 + 0.37)));
    constexpr float LAM   = (float)(3130.0 * 0.37 / ((1.0 + 0.37) * (1.0 - 2.0 * 0.37)));
    constexpr float SIG_Y = 64.8f;
    constexpr float H_ISO = 300.0f;
    const float TWO_MU  = 2.0f * MU;
    const float INV_DEN = 1.0f / (3.0f * MU + H_ISO);
    const float K3P     = (3.0f * MU) * INV_DEN;      // k = K3P * fY * rq_u
    const float HP      = H_ISO * INV_DEN;            // Y += HP * fY
    const float CSC     = 1.0f / (MU * 2.4494897427831781f);  // 1/(MU*sqrt6)
    const float Y0      = SIG_Y * CSC;

    const int tid = threadIdx.x;
    const int g   = tid >> 3;       // local batch 0..31
    const int l   = tid & 7;        // lane in 8-group; points (l, l+8)
    const int gb  = blockIdx.x * BPB + g;   // global batch

    const float* xb = x + gb * ROWF;
    float* ob = out + gb * ROWF;

    // ---- packed per-thread weights: .x = point l, .y = point l+8 ----
    // w1 row 2 pre-halved (tensorial shear), so ee_xy = w1p[2].x - p3 directly.
    const int pa = l, pb = l + 8;
    v2 w1p[3][3], w2p[3][3];
    #pragma unroll
    for (int c = 0; c < 3; ++c)
        #pragma unroll
        for (int f = 0; f < 3; ++f) {
            float s = (c == 2) ? 0.5f : 1.0f;
            w1p[c][f].x = s * W1[(3 * pa + c) * 3 + f];
            w1p[c][f].y = s * W1[(3 * pb + c) * 3 + f];
        }
    #pragma unroll
    for (int o = 0; o < 3; ++o)
        #pragma unroll
        for (int c = 0; c < 3; ++c) {
            float wa = W2[o * 48 + 3 * pa + c];
            float wb = W2[o * 48 + 3 * pb + c];
            w2p[o][c].x = fmaxf(wa, 0.0f) + log1pf(expf(-fabsf(wa)));
            w2p[o][c].y = fmaxf(wb, 0.0f) + log1pf(expf(-fabsf(wb)));
        }

    // ---- constant elastic map M[o][f] = sum_p w2s_p . C . W1_p ----
    // (Ce)_xx row = (LAM+2MU) w1[0] + LAM w1[1];  yy analogous;
    // (Ce)_xy row = 2MU * w1p[2]  (w1p[2] already halved).
    float Mrow[3];   // this lane's output-component row (l<3), else junk
    {
        float Ms[3][3];
        #pragma unroll
        for (int f = 0; f < 3; ++f) {
            v2 ax = (LAM + TWO_MU) * w1p[0][f] + LAM * w1p[1][f];
            v2 ay = LAM * w1p[0][f] + (LAM + TWO_MU) * w1p[1][f];
            v2 as = TWO_MU * w1p[2][f];
            #pragma unroll
            for (int o = 0; o < 3; ++o) {
                v2 mp = vfma(w2p[o][0], ax, vfma(w2p[o][1], ay, w2p[o][2] * as));
                float ms = mp.x + mp.y;
                RED8(ms);               // sum over the 8 lanes (all 16 points)
                Ms[o][f] = ms;
            }
        }
        #pragma unroll
        for (int f = 0; f < 3; ++f) {
            float v = (l == 0) ? Ms[0][f] : ((l == 1) ? Ms[1][f] : Ms[2][f]);
            Mrow[f] = v;
        }
    }

    v2 p0 = {0.f,0.f}, p1 = {0.f,0.f}, p2 = {0.f,0.f}, p3 = {0.f,0.f};
    v2 Y  = {Y0, Y0};
    v2 z0 = {0.f,0.f}, z1 = {0.f,0.f}, z2 = {0.f,0.f};

    const float4* xv = (const float4*)xb;   // group-uniform broadcast loads
    const bool wact = (l < 3);
    float* obl = ob + l;

#define J2_PHYS(x0_, x1_, x2_, rr, mxv)                                      \
  {                                                                          \
    const float x0s = (x0_), x1s = (x1_), x2s = (x2_);                       \
    const v2 x0 = {x0s, x0s}, x1 = {x1s, x1s}, x2 = {x2s, x2s};              \
    const v2 ee_xx = vfma(w1p[0][0], x0, vfma(w1p[0][1], x1,                 \
                          vfma(w1p[0][2], x2, -p0)));                        \
    const v2 ee_yy = vfma(w1p[1][0], x0, vfma(w1p[1][1], x1,                 \
                          vfma(w1p[1][2], x2, -p1)));                        \
    const v2 ee_xy = vfma(w1p[2][0], x0, vfma(w1p[2][1], x1,                 \
                          vfma(w1p[2][2], x2, -p3)));                        \
    const v2 tr = (ee_xx + ee_yy) - p2;                                      \
    const v2 c3 = tr * (1.0f / 3.0f);                                        \
    const v2 exd = ee_xx - c3;                                               \
    const v2 eyd = ee_yy - c3;                                               \
    const v2 szd = exd + eyd;           /* = -ezd */                         \
    const v2 t2 = ee_xy * ee_xy;                                             \
    v2 u = exd * exd;                                                        \
    u = vfma(eyd, eyd, u);                                                   \
    u = vfma(szd, szd, u);                                                   \
    u = vfma(t2, (v2){2.0f, 2.0f}, u);                                       \
    u = vmax(u, (v2){1e-30f, 1e-30f});                                       \
    v2 rq;                                                                   \
    rq.x = __builtin_amdgcn_rsqf(u.x);                                       \
    rq.y = __builtin_amdgcn_rsqf(u.y);                                       \
    const v2 su = u * rq;               /* sqrt(u) */                        \
    const v2 fY = vmax(su - Y, (v2){0.0f, 0.0f});                            \
    Y = vfma((v2){HP, HP}, fY, Y);                                           \
    const v2 k = (K3P * fY) * rq;                                            \
    const v2 kdx = k * exd;                                                  \
    const v2 kdy = k * eyd;                                                  \
    const v2 kdxy = k * ee_xy;                                               \
    p0 += kdx;                                                               \
    p1 += kdy;                                                               \
    p3 += kdxy;                                                              \
    p2 = p2 - k * szd;                                                       \
    z0 = vfma(w2p[0][0], kdx, vfma(w2p[0][1], kdy, vfma(w2p[0][2], kdxy, z0)));\
    z1 = vfma(w2p[1][0], kdx, vfma(w2p[1][1], kdy, vfma(w2p[1][2], kdxy, z1)));\
    z2 = vfma(w2p[2][0], kdx, vfma(w2p[2][1], kdy, vfma(w2p[2][2], kdxy, z2)));\
    (rr)[0] = z0.x + z0.y;                                                   \
    (rr)[1] = z1.x + z1.y;                                                   \
    (rr)[2] = z2.x + z2.y;                                                   \
    (mxv) = fmaf(Mrow[0], x0s, fmaf(Mrow[1], x1s, Mrow[2] * x2s));           \
  }

    float4 A0 = xv[0], A1 = xv[1], A2 = xv[2];

    for (int tb = 0; tb < TSTEPS / 4; ++tb) {
        // distance-1 prefetch; last iteration re-loads the same block (no OOB)
        const int nb = (tb < TSTEPS / 4 - 1) ? (3 * tb + 3) : (3 * tb);
        float4 An0 = xv[nb + 0];
        float4 An1 = xv[nb + 1];
        float4 An2 = xv[nb + 2];

        float r[12], mx[4];
        J2_PHYS(A0.x,  A0.y,  A0.z,  r + 0, mx[0]);
        J2_PHYS(A0.w,  A1.x,  A1.y,  r + 3, mx[1]);
        J2_PHYS(A1.z,  A1.w,  A2.x,  r + 6, mx[2]);
        J2_PHYS(A2.y,  A2.z,  A2.w,  r + 9, mx[3]);

        // sum the 12 cumulative-Z snapshots across the 8-lane group
        DPP_BFLY12(r[0], r[1], r[2], r[3], r[4], r[5],
                   r[6], r[7], r[8], r[9], r[10], r[11]);

        if (wact) {
            // lane l writes component l: out = M.x - 2MU * Z
            float zz0 = (l == 0) ? r[0] : ((l == 1) ? r[1]  : r[2]);
            float zz1 = (l == 0) ? r[3] : ((l == 1) ? r[4]  : r[5]);
            float zz2 = (l == 0) ? r[6] : ((l == 1) ? r[7]  : r[8]);
            float zz3 = (l == 0) ? r[9] : ((l == 1) ? r[10] : r[11]);
            obl[12 * tb + 0] = fmaf(-TWO_MU, zz0, mx[0]);
            obl[12 * tb + 3] = fmaf(-TWO_MU, zz1, mx[1]);
            obl[12 * tb + 6] = fmaf(-TWO_MU, zz2, mx[2]);
            obl[12 * tb + 9] = fmaf(-TWO_MU, zz3, mx[3]);
        }

        A0 = An0; A1 = An1; A2 = An2;
    }
#undef J2_PHYS
}

extern "C" void kernel_launch(void* const* d_in, const int* in_sizes, int n_in,
                              void* d_out, int out_size, void* d_ws, size_t ws_size,
                              hipStream_t stream) {
    const float* x  = (const float*)d_in[0];
    const float* W1 = (const float*)d_in[1];
    const float* W2 = (const float*)d_in[2];
    float* out = (float*)d_out;

    const int B = 16384;
    dim3 grid(B / BPB);   // 512 blocks
    dim3 block(BLOCK);
    prnn_j2_kernel<<<grid, block, 0, stream>>>(x, W1, W2, out);
}